// Round 4
// baseline (748.907 us; speedup 1.0000x reference)
//
#include <hip/hip_runtime.h>

// TopK-mask: per row of [16384, 4096] f32, keep the 64 largest, zero the rest.
// One 256-thread block per row; keys = order-preserving uint32 transform.
// Radix select, digits 11+11+10 (MSB first), LDS histograms 2048/2048/1024 bins.
// Ties at the K-th value: lowest index wins (matches jax.lax.top_k).
//
// Structure: single upfront vectorized zero of both hist regions (pass-2
// region re-zeroed concurrently with pass-1 atomics); all-wave shuffle scans
// (no LDS scan round-trips); per-region padding keeps every strided bin read
// at the free 2-lanes/bank level. 11 barriers total.
// Output via nontemporal stores (out never re-read: keep L2/L3 for x).

#define COLS 4096
#define KTOP 64u
#define NT 256
#define EPT 16            // elements per thread (COLS / NT)
#define H11 2304          // 2048 bins + (b>>3) padding
#define H10 1280          // 1024 bins + (b>>2) padding (reuses region A)

typedef float  fx4 __attribute__((ext_vector_type(4)));   // native vec: nt-store OK

__device__ __forceinline__ unsigned pad8(unsigned b) { return b + (b >> 3); }
__device__ __forceinline__ unsigned pad4(unsigned b) { return b + (b >> 2); }

__global__ __launch_bounds__(NT, 8) void topk_mask_kernel(const float* __restrict__ x,
                                                          float* __restrict__ out) {
    const int row = blockIdx.x;
    const int t = threadIdx.x;
    const unsigned lane = t & 63u;
    const unsigned w = t >> 6;

    const float* __restrict__ xr = x + (size_t)row * COLS;
    float* __restrict__ orow = out + (size_t)row * COLS;

    __shared__ alignas(16) unsigned histmem[2 * H11];  // A: [0,H11)  B: [H11,2*H11)
    __shared__ unsigned scw[4];
    __shared__ unsigned sh_selbin, sh_selS;

    unsigned* histA = histmem;
    unsigned* histB = histmem + H11;

    // ---- Load 16 contiguous floats per thread; convert to sortable keys ----
    unsigned key[EPT];
    const float4* xv = reinterpret_cast<const float4*>(xr) + t * 4;
    #pragma unroll
    for (int c = 0; c < 4; ++c) {
        float4 v = xv[c];
        float f[4] = {v.x, v.y, v.z, v.w};
        #pragma unroll
        for (int j = 0; j < 4; ++j) {
            unsigned u = __float_as_uint(f[j]);
            key[4 * c + j] = (u & 0x80000000u) ? ~u : (u | 0x80000000u);
        }
    }

    // ---- Zero both histogram regions, vectorized ----
    {
        uint4* hz = reinterpret_cast<uint4*>(histmem);
        #pragma unroll
        for (int i = 0; i < 5; ++i) {
            unsigned idx = t + NT * i;
            if (idx < (2 * H11) / 4) hz[idx] = make_uint4(0u, 0u, 0u, 0u);
        }
    }
    __syncthreads();                                                   // B1

    unsigned need = KTOP;
    unsigned prefix = 0;
    unsigned T = 0;

    // ================= Pass 0: 2048 bins over key[31:21] =================
    #pragma unroll
    for (int j = 0; j < EPT; ++j) atomicAdd(&histA[pad8(key[j] >> 21)], 1u);
    __syncthreads();                                                   // B2
    {
        unsigned hr[8];
        unsigned L = 0;
        const unsigned base = 9u * t;             // pad8(8t+i) = 9t+i, i<8
        #pragma unroll
        for (int i = 0; i < 8; ++i) { hr[i] = histA[base + i]; L += hr[i]; }

        unsigned suf = L;                         // intra-wave inclusive suffix scan
        #pragma unroll
        for (int d = 1; d < 64; d <<= 1) {
            unsigned o = __shfl_down(suf, d, 64);
            if (lane + d < 64) suf += o;
        }
        if (lane == 0) scw[w] = suf;              // wave total
        __syncthreads();                                               // B3
        unsigned S = suf - L;                     // excl suffix within wave
        #pragma unroll
        for (int w2 = 1; w2 < 4; ++w2) if (w2 > (int)w) S += scw[w2];

        #pragma unroll
        for (int i = 7; i >= 0; --i) {
            unsigned h = hr[i], Sn = S + h;
            if (S < need && need <= Sn) { sh_selbin = 8u * t + i; sh_selS = S; }
            S = Sn;
        }
        __syncthreads();                                               // B4
        prefix = sh_selbin;                       // 11-bit prefix
        need -= sh_selS;
    }

    // ======== Pass 1: 2048 bins over key[20:10], prefix-filtered ========
    {
        // concurrently re-zero region A's first H10 words for pass 2
        uint4* hzA = reinterpret_cast<uint4*>(histA);
        #pragma unroll
        for (int i = 0; i < 2; ++i) {
            unsigned idx = t + NT * i;
            if (idx < H10 / 4) hzA[idx] = make_uint4(0u, 0u, 0u, 0u);
        }
        #pragma unroll
        for (int j = 0; j < EPT; ++j) {
            unsigned k = key[j];
            if ((k >> 21) == prefix) atomicAdd(&histB[pad8((k >> 10) & 0x7FFu)], 1u);
        }
        __syncthreads();                                               // B5

        unsigned hr[8];
        unsigned L = 0;
        const unsigned base = 9u * t;
        #pragma unroll
        for (int i = 0; i < 8; ++i) { hr[i] = histB[base + i]; L += hr[i]; }

        unsigned suf = L;
        #pragma unroll
        for (int d = 1; d < 64; d <<= 1) {
            unsigned o = __shfl_down(suf, d, 64);
            if (lane + d < 64) suf += o;
        }
        if (lane == 0) scw[w] = suf;
        __syncthreads();                                               // B6
        unsigned S = suf - L;
        #pragma unroll
        for (int w2 = 1; w2 < 4; ++w2) if (w2 > (int)w) S += scw[w2];

        #pragma unroll
        for (int i = 7; i >= 0; --i) {
            unsigned h = hr[i], Sn = S + h;
            if (S < need && need <= Sn) { sh_selbin = 8u * t + i; sh_selS = S; }
            S = Sn;
        }
        __syncthreads();                                               // B7
        prefix = (prefix << 11) | sh_selbin;      // 22-bit prefix
        need -= sh_selS;
    }

    // ======== Pass 2: 1024 bins over key[9:0], prefix-filtered ========
    {
        #pragma unroll
        for (int j = 0; j < EPT; ++j) {
            unsigned k = key[j];
            if ((k >> 10) == prefix) atomicAdd(&histA[pad4(k & 0x3FFu)], 1u);
        }
        __syncthreads();                                               // B8

        unsigned hr[4];
        unsigned L = 0;
        const unsigned base = 5u * t;             // pad4(4t+i) = 5t+i, i<4
        #pragma unroll
        for (int i = 0; i < 4; ++i) { hr[i] = histA[base + i]; L += hr[i]; }

        unsigned suf = L;
        #pragma unroll
        for (int d = 1; d < 64; d <<= 1) {
            unsigned o = __shfl_down(suf, d, 64);
            if (lane + d < 64) suf += o;
        }
        if (lane == 0) scw[w] = suf;
        __syncthreads();                                               // B9
        unsigned S = suf - L;
        #pragma unroll
        for (int w2 = 1; w2 < 4; ++w2) if (w2 > (int)w) S += scw[w2];

        #pragma unroll
        for (int i = 3; i >= 0; --i) {
            unsigned h = hr[i], Sn = S + h;
            if (S < need && need <= Sn) { sh_selbin = 4u * t + i; sh_selS = S; }
            S = Sn;
        }
        __syncthreads();                                               // B10
        T = (prefix << 10) | sh_selbin;           // full 32-bit threshold key
        need -= sh_selS;
    }

    // ---- Stable rank among key==T elements (index order == (t,j) order) ----
    unsigned eq = 0;
    #pragma unroll
    for (int j = 0; j < EPT; ++j) eq += (key[j] == T) ? 1u : 0u;
    unsigned pre = eq;                            // intra-wave inclusive prefix scan
    #pragma unroll
    for (int d = 1; d < 64; d <<= 1) {
        unsigned o = __shfl_up(pre, d, 64);
        if (lane >= (unsigned)d) pre += o;
    }
    if (lane == 63) scw[w] = pre;                 // wave total
    __syncthreads();                                                   // B11
    unsigned rank = pre - eq;
    #pragma unroll
    for (int w2 = 0; w2 < 3; ++w2) if (w2 < (int)w) rank += scw[w2];

    // ---- Output: keep key>T always; key==T only for first `need` by index ----
    fx4* ov = reinterpret_cast<fx4*>(orow) + t * 4;
    #pragma unroll
    for (int c = 0; c < 4; ++c) {
        float r[4];
        #pragma unroll
        for (int j = 0; j < 4; ++j) {
            unsigned k = key[4 * c + j];
            bool inc;
            if (k > T)       inc = true;
            else if (k == T) { inc = (rank < need); rank += 1u; }
            else             inc = false;
            unsigned u = (k & 0x80000000u) ? (k ^ 0x80000000u) : ~k;
            r[j] = inc ? __uint_as_float(u) : 0.0f;
        }
        fx4 o4 = {r[0], r[1], r[2], r[3]};
        __builtin_nontemporal_store(o4, &ov[c]);  // out never re-read: keep L2/L3 for x
    }
}

extern "C" void kernel_launch(void* const* d_in, const int* in_sizes, int n_in,
                              void* d_out, int out_size, void* d_ws, size_t ws_size,
                              hipStream_t stream) {
    const float* x = (const float*)d_in[0];
    float* out = (float*)d_out;
    const int rows = in_sizes[0] / COLS;  // 16384
    topk_mask_kernel<<<rows, NT, 0, stream>>>(x, out);
}

// Round 5
// 437.162 us; speedup vs baseline: 1.7131x; 1.7131x over previous
//
#include <hip/hip_runtime.h>

// TopK-mask: per row of [16384, 4096] f32, keep the 64 largest, zero the rest.
// One 256-thread block per row; keys = order-preserving uint32 transform.
// Radix select, digits 11+11+10 (MSB first), LDS histograms 2048/2048/1024 bins.
// Ties at the K-th value: lowest index wins (matches jax.lax.top_k).
//
// Structure: single upfront vectorized zero of both hist regions (pass-2
// region re-zeroed concurrently with pass-1 atomics); all-wave shuffle scans
// (no LDS scan round-trips); per-region padding keeps every strided bin read
// at the free 2-lanes/bank level. 11 barriers total.
//
// NOTE (R4 lesson): __builtin_nontemporal_store on the output REGRESSED 3x —
// WRITE_SIZE 262MB -> 711MB, kernel 130 -> 468 us. gfx950 'nt' bypasses L2
// write-combining and amplifies HBM write traffic. Use plain stores.

#define COLS 4096
#define KTOP 64u
#define NT 256
#define EPT 16            // elements per thread (COLS / NT)
#define H11 2304          // 2048 bins + (b>>3) padding
#define H10 1280          // 1024 bins + (b>>2) padding (reuses region A)

__device__ __forceinline__ unsigned pad8(unsigned b) { return b + (b >> 3); }
__device__ __forceinline__ unsigned pad4(unsigned b) { return b + (b >> 2); }

__global__ __launch_bounds__(NT, 8) void topk_mask_kernel(const float* __restrict__ x,
                                                          float* __restrict__ out) {
    const int row = blockIdx.x;
    const int t = threadIdx.x;
    const unsigned lane = t & 63u;
    const unsigned w = t >> 6;

    const float* __restrict__ xr = x + (size_t)row * COLS;
    float* __restrict__ orow = out + (size_t)row * COLS;

    __shared__ alignas(16) unsigned histmem[2 * H11];  // A: [0,H11)  B: [H11,2*H11)
    __shared__ unsigned scw[4];
    __shared__ unsigned sh_selbin, sh_selS;

    unsigned* histA = histmem;
    unsigned* histB = histmem + H11;

    // ---- Load 16 contiguous floats per thread; convert to sortable keys ----
    unsigned key[EPT];
    const float4* xv = reinterpret_cast<const float4*>(xr) + t * 4;
    #pragma unroll
    for (int c = 0; c < 4; ++c) {
        float4 v = xv[c];
        float f[4] = {v.x, v.y, v.z, v.w};
        #pragma unroll
        for (int j = 0; j < 4; ++j) {
            unsigned u = __float_as_uint(f[j]);
            key[4 * c + j] = (u & 0x80000000u) ? ~u : (u | 0x80000000u);
        }
    }

    // ---- Zero both histogram regions, vectorized ----
    {
        uint4* hz = reinterpret_cast<uint4*>(histmem);
        #pragma unroll
        for (int i = 0; i < 5; ++i) {
            unsigned idx = t + NT * i;
            if (idx < (2 * H11) / 4) hz[idx] = make_uint4(0u, 0u, 0u, 0u);
        }
    }
    __syncthreads();                                                   // B1

    unsigned need = KTOP;
    unsigned prefix = 0;
    unsigned T = 0;

    // ================= Pass 0: 2048 bins over key[31:21] =================
    #pragma unroll
    for (int j = 0; j < EPT; ++j) atomicAdd(&histA[pad8(key[j] >> 21)], 1u);
    __syncthreads();                                                   // B2
    {
        unsigned hr[8];
        unsigned L = 0;
        const unsigned base = 9u * t;             // pad8(8t+i) = 9t+i, i<8
        #pragma unroll
        for (int i = 0; i < 8; ++i) { hr[i] = histA[base + i]; L += hr[i]; }

        unsigned suf = L;                         // intra-wave inclusive suffix scan
        #pragma unroll
        for (int d = 1; d < 64; d <<= 1) {
            unsigned o = __shfl_down(suf, d, 64);
            if (lane + d < 64) suf += o;
        }
        if (lane == 0) scw[w] = suf;              // wave total
        __syncthreads();                                               // B3
        unsigned S = suf - L;                     // excl suffix within wave
        #pragma unroll
        for (int w2 = 1; w2 < 4; ++w2) if (w2 > (int)w) S += scw[w2];

        #pragma unroll
        for (int i = 7; i >= 0; --i) {
            unsigned h = hr[i], Sn = S + h;
            if (S < need && need <= Sn) { sh_selbin = 8u * t + i; sh_selS = S; }
            S = Sn;
        }
        __syncthreads();                                               // B4
        prefix = sh_selbin;                       // 11-bit prefix
        need -= sh_selS;
    }

    // ======== Pass 1: 2048 bins over key[20:10], prefix-filtered ========
    {
        // concurrently re-zero region A's first H10 words for pass 2
        uint4* hzA = reinterpret_cast<uint4*>(histA);
        #pragma unroll
        for (int i = 0; i < 2; ++i) {
            unsigned idx = t + NT * i;
            if (idx < H10 / 4) hzA[idx] = make_uint4(0u, 0u, 0u, 0u);
        }
        #pragma unroll
        for (int j = 0; j < EPT; ++j) {
            unsigned k = key[j];
            if ((k >> 21) == prefix) atomicAdd(&histB[pad8((k >> 10) & 0x7FFu)], 1u);
        }
        __syncthreads();                                               // B5

        unsigned hr[8];
        unsigned L = 0;
        const unsigned base = 9u * t;
        #pragma unroll
        for (int i = 0; i < 8; ++i) { hr[i] = histB[base + i]; L += hr[i]; }

        unsigned suf = L;
        #pragma unroll
        for (int d = 1; d < 64; d <<= 1) {
            unsigned o = __shfl_down(suf, d, 64);
            if (lane + d < 64) suf += o;
        }
        if (lane == 0) scw[w] = suf;
        __syncthreads();                                               // B6
        unsigned S = suf - L;
        #pragma unroll
        for (int w2 = 1; w2 < 4; ++w2) if (w2 > (int)w) S += scw[w2];

        #pragma unroll
        for (int i = 7; i >= 0; --i) {
            unsigned h = hr[i], Sn = S + h;
            if (S < need && need <= Sn) { sh_selbin = 8u * t + i; sh_selS = S; }
            S = Sn;
        }
        __syncthreads();                                               // B7
        prefix = (prefix << 11) | sh_selbin;      // 22-bit prefix
        need -= sh_selS;
    }

    // ======== Pass 2: 1024 bins over key[9:0], prefix-filtered ========
    {
        #pragma unroll
        for (int j = 0; j < EPT; ++j) {
            unsigned k = key[j];
            if ((k >> 10) == prefix) atomicAdd(&histA[pad4(k & 0x3FFu)], 1u);
        }
        __syncthreads();                                               // B8

        unsigned hr[4];
        unsigned L = 0;
        const unsigned base = 5u * t;             // pad4(4t+i) = 5t+i, i<4
        #pragma unroll
        for (int i = 0; i < 4; ++i) { hr[i] = histA[base + i]; L += hr[i]; }

        unsigned suf = L;
        #pragma unroll
        for (int d = 1; d < 64; d <<= 1) {
            unsigned o = __shfl_down(suf, d, 64);
            if (lane + d < 64) suf += o;
        }
        if (lane == 0) scw[w] = suf;
        __syncthreads();                                               // B9
        unsigned S = suf - L;
        #pragma unroll
        for (int w2 = 1; w2 < 4; ++w2) if (w2 > (int)w) S += scw[w2];

        #pragma unroll
        for (int i = 3; i >= 0; --i) {
            unsigned h = hr[i], Sn = S + h;
            if (S < need && need <= Sn) { sh_selbin = 4u * t + i; sh_selS = S; }
            S = Sn;
        }
        __syncthreads();                                               // B10
        T = (prefix << 10) | sh_selbin;           // full 32-bit threshold key
        need -= sh_selS;
    }

    // ---- Stable rank among key==T elements (index order == (t,j) order) ----
    unsigned eq = 0;
    #pragma unroll
    for (int j = 0; j < EPT; ++j) eq += (key[j] == T) ? 1u : 0u;
    unsigned pre = eq;                            // intra-wave inclusive prefix scan
    #pragma unroll
    for (int d = 1; d < 64; d <<= 1) {
        unsigned o = __shfl_up(pre, d, 64);
        if (lane >= (unsigned)d) pre += o;
    }
    if (lane == 63) scw[w] = pre;                 // wave total
    __syncthreads();                                                   // B11
    unsigned rank = pre - eq;
    #pragma unroll
    for (int w2 = 0; w2 < 3; ++w2) if (w2 < (int)w) rank += scw[w2];

    // ---- Output: keep key>T always; key==T only for first `need` by index ----
    float4* ov = reinterpret_cast<float4*>(orow) + t * 4;
    #pragma unroll
    for (int c = 0; c < 4; ++c) {
        float r[4];
        #pragma unroll
        for (int j = 0; j < 4; ++j) {
            unsigned k = key[4 * c + j];
            bool inc;
            if (k > T)       inc = true;
            else if (k == T) { inc = (rank < need); rank += 1u; }
            else             inc = false;
            unsigned u = (k & 0x80000000u) ? (k ^ 0x80000000u) : ~k;
            r[j] = inc ? __uint_as_float(u) : 0.0f;
        }
        float4 o4;
        o4.x = r[0]; o4.y = r[1]; o4.z = r[2]; o4.w = r[3];
        ov[c] = o4;   // plain store: L2 write-combines to full lines
    }
}

extern "C" void kernel_launch(void* const* d_in, const int* in_sizes, int n_in,
                              void* d_out, int out_size, void* d_ws, size_t ws_size,
                              hipStream_t stream) {
    const float* x = (const float*)d_in[0];
    float* out = (float*)d_out;
    const int rows = in_sizes[0] / COLS;  // 16384
    topk_mask_kernel<<<rows, NT, 0, stream>>>(x, out);
}